// Round 4
// baseline (340.164 us; speedup 1.0000x reference)
//
#include <hip/hip_runtime.h>
#include <cstdint>
#include <cstddef>

// Problem: B=32, C=768, H=W=32 (HW=1024).
// out[b,c,hw] = (0.5 + 0.5 * cos_gate(b,c)) * X[b,c,hw]
// cos_gate = dot(K_c,V_c)/((||K_c||+1e-12)(||V_c||+1e-12)),
// K = Wk @ Xn, V = Wv @ Xn, Xn = X * rsqrt(mean_c X^2 + 1e-6).
//
// r4: persistent gemm. Grid = 256 blocks exactly (1/CU, one dispatch round);
// each block runs 3 c-tile items back-to-back over the SAME B slice with the
// 8-phase pipeline never draining (item boundaries = acc dump only; the old
// wrap dead-stages become real prefetches of the next item's A tile).

#define B_   32
#define C_   768
#define HW_  1024
#define CHW_ (C_ * HW_)          // 786432
#define EPS_NORM 1e-6f
#define EPS_COS  1e-12f

using f32x4  = __attribute__((ext_vector_type(4))) float;
using bf16x8 = __attribute__((ext_vector_type(8))) short;   // 8 bf16 = 4 VGPRs

__device__ inline unsigned short f2bf(float f) {
    union { float f; unsigned u; } v; v.f = f;
    unsigned u = v.u;
    u += 0x7fffu + ((u >> 16) & 1u);        // round-to-nearest-even
    return (unsigned short)(u >> 16);
}

// async global->LDS, 16 B per lane. LDS dst is wave-uniform base + lane*16.
__device__ __forceinline__ void load16_lds(const unsigned short* g, short* l) {
    __builtin_amdgcn_global_load_lds(
        (const __attribute__((address_space(1))) unsigned int*)g,
        (__attribute__((address_space(3))) unsigned int*)l,
        16, 0, 0);
}

__device__ __forceinline__ void stage_half(const unsigned short* g, short* l,
                                           size_t toff, int ldsoff, int rs) {
    load16_lds(g + toff,                     l + ldsoff);
    load16_lds(g + toff + (size_t)rs * 768,  l + ldsoff + 4096);
}

// ---------------------------------------------------------------------------
// K1: cast + row-interleave first 1536 rows of W_in (fp32) -> bf16.
// Wst[2c+s] = W[s*768 + c]. grid 1536 blocks x 192 threads (1 float4/thread).
// ---------------------------------------------------------------------------
__global__ void wconv_kernel(const float* __restrict__ W, unsigned short* __restrict__ Wst) {
    const int orow = blockIdx.x;               // 0..1535
    const int c4   = threadIdx.x;              // 0..191
    const int irow = (orow & 1) * 768 + (orow >> 1);
    const float4 v = reinterpret_cast<const float4*>(W + (size_t)irow * 768)[c4];
    ushort4 o;
    o.x = f2bf(v.x); o.y = f2bf(v.y); o.z = f2bf(v.z); o.w = f2bf(v.w);
    reinterpret_cast<ushort4*>(Wst + (size_t)orow * 768)[c4] = o;
}

// ---------------------------------------------------------------------------
// K2 (fused sumsq + normalize + transpose): unchanged from r3.
// ---------------------------------------------------------------------------
__global__ __launch_bounds__(256) void norm_kernel(const float* __restrict__ X,
                                                   unsigned short* __restrict__ Xnt) {
    const int b   = blockIdx.y;
    const int hw0 = blockIdx.x * 64;
    const int tid = threadIdx.x;
    __shared__ float4 P[256];          // partials, then per-hw-quad scales in P[0..15]
    __shared__ short  T[64][78];       // transpose tile (pad 78: ~2-way, free)

    const int cg = tid >> 4;           // c group 0..15
    const int q4 = tid & 15;           // hw quad 0..15
    const float* xb = X + (size_t)b * CHW_ + hw0 + q4 * 4;
    float4 s = {0.f, 0.f, 0.f, 0.f};
    #pragma unroll 4
    for (int c = cg; c < 768; c += 16) {
        float4 v = *reinterpret_cast<const float4*>(xb + (size_t)c * HW_);
        s.x += v.x * v.x; s.y += v.y * v.y; s.z += v.z * v.z; s.w += v.w * v.w;
    }
    P[tid] = s;
    __syncthreads();
    if (tid < 16) {
        float4 a = P[tid];
        #pragma unroll
        for (int g = 1; g < 16; ++g) {
            float4 v = P[g * 16 + tid];
            a.x += v.x; a.y += v.y; a.z += v.z; a.w += v.w;
        }
        float4 sc;
        sc.x = rsqrtf(a.x * (1.f / 768.f) + EPS_NORM);
        sc.y = rsqrtf(a.y * (1.f / 768.f) + EPS_NORM);
        sc.z = rsqrtf(a.z * (1.f / 768.f) + EPS_NORM);
        sc.w = rsqrtf(a.w * (1.f / 768.f) + EPS_NORM);
        P[tid] = sc;
    }
    __syncthreads();

    #pragma unroll 1
    for (int ch = 0; ch < 12; ++ch) {
        const int c0 = ch * 64;
        #pragma unroll
        for (int it = 0; it < 4; ++it) {
            int q  = it * 256 + tid;    // 0..1023
            int r  = q >> 4;            // c row in tile
            int c4 = (q & 15) * 4;      // hw col in tile
            const float4 x = *reinterpret_cast<const float4*>(
                X + (size_t)b * CHW_ + (size_t)(c0 + r) * HW_ + hw0 + c4);
            const float4 sc = P[q & 15];
            ushort4 o;
            o.x = f2bf(x.x * sc.x); o.y = f2bf(x.y * sc.y);
            o.z = f2bf(x.z * sc.z); o.w = f2bf(x.w * sc.w);
            *reinterpret_cast<ushort4*>(&T[r][c4]) = o;
        }
        __syncthreads();
        #pragma unroll
        for (int it = 0; it < 2; ++it) {
            int q  = it * 256 + tid;    // 0..511
            int rp = q >> 3;            // hw row
            int cc = (q & 7) * 8;       // c chunk
            __align__(16) unsigned short tmp[8];
            #pragma unroll
            for (int j = 0; j < 8; ++j) tmp[j] = (unsigned short)T[cc + j][rp];
            *reinterpret_cast<uint4*>(
                Xnt + (size_t)b * CHW_ + (size_t)(hw0 + rp) * C_ + c0 + cc) =
                *reinterpret_cast<const uint4*>(tmp);
        }
        __syncthreads();
    }
}

// ---------------------------------------------------------------------------
// K4: persistent 256x256 (BK=64) 8-phase GEMM, 3 c-tile items per block.
// Grid (8,32): x = (n-tile<<1)|g, y = b. Items: c0 = (g*3+item)*256, same
// (b,n0) B slice for all items. 36 K-tiles, T = 0..35, item = T/12,
// k = (T%12)*64. Stage targets keyed by T parity exactly as r1 (buf = T&1);
// only global pointers change per item. Tail clamp T>35 -> T-2 (parity- and
// content-preserving identical-byte rewrite: race-free dead stage).
// vmcnt(6) guards at phases 4/8 as r1 (3-phase-old stage completion).
// ---------------------------------------------------------------------------
template<int P, bool VM>
__device__ __forceinline__ void phase(const short* Ar, const short* Br,
        const unsigned short* gs, short* ls, size_t toff, int ldsoff, int rs,
        int l15, int wgm64, int wnl64, int slot0, int slot1,
        bf16x8 (&bA)[2][2], bf16x8 (&bB)[4][2], f32x4 (&acc)[8][4]) {
    if constexpr (P == 0) {            // B-frags loaded once per K-tile
        #pragma unroll
        for (int ni = 0; ni < 4; ++ni) {
            const int rB = wnl64 + (ni << 4) + l15;
            bB[ni][0] = *reinterpret_cast<const bf16x8*>(Br + (rB << 6) + slot0);
            bB[ni][1] = *reinterpret_cast<const bf16x8*>(Br + (rB << 6) + slot1);
        }
    }
    #pragma unroll
    for (int s = 0; s < 2; ++s) {      // A-frags mi = 2P, 2P+1
        const int rA = ((((P & 1) << 1) | s) << 4) + l15 + wgm64;
        bA[s][0] = *reinterpret_cast<const bf16x8*>(Ar + (rA << 6) + slot0);
        bA[s][1] = *reinterpret_cast<const bf16x8*>(Ar + (rA << 6) + slot1);
    }
    stage_half(gs, ls, toff, ldsoff, rs);
    if (VM) asm volatile("s_waitcnt vmcnt(6)" ::: "memory");
    __builtin_amdgcn_sched_barrier(0);
    __builtin_amdgcn_s_barrier();
    asm volatile("s_waitcnt lgkmcnt(0)" ::: "memory");
    __builtin_amdgcn_sched_barrier(0);
    __builtin_amdgcn_s_setprio(1);
    #pragma unroll
    for (int s = 0; s < 2; ++s)
        #pragma unroll
        for (int ni = 0; ni < 4; ++ni) {
            acc[(P << 1) | s][ni] = __builtin_amdgcn_mfma_f32_16x16x32_bf16(
                bA[s][0], bB[ni][0], acc[(P << 1) | s][ni], 0, 0, 0);
            acc[(P << 1) | s][ni] = __builtin_amdgcn_mfma_f32_16x16x32_bf16(
                bA[s][1], bB[ni][1], acc[(P << 1) | s][ni], 0, 0, 0);
        }
    __builtin_amdgcn_s_setprio(0);
    __builtin_amdgcn_sched_barrier(0);
    __builtin_amdgcn_s_barrier();
    __builtin_amdgcn_sched_barrier(0);
}

__device__ __forceinline__ void dump_acc(f32x4 (&acc)[8][4], float* __restrict__ wsA,
                                         int b, int c0, int wgm64, int quad, int l15) {
    #pragma unroll
    for (int mi = 0; mi < 8; ++mi) {
        float d0 = 0.f, e0 = 0.f, f0 = 0.f, d1 = 0.f, e1 = 0.f, f1 = 0.f;
        #pragma unroll
        for (int ni = 0; ni < 4; ++ni) {
            f32x4 a = acc[mi][ni];
            d0 += a[0] * a[1]; e0 += a[0] * a[0]; f0 += a[1] * a[1];
            d1 += a[2] * a[3]; e1 += a[2] * a[2]; f1 += a[3] * a[3];
            acc[mi][ni] = (f32x4){0.f, 0.f, 0.f, 0.f};
        }
        #pragma unroll
        for (int off = 1; off < 16; off <<= 1) {
            d0 += __shfl_xor(d0, off); e0 += __shfl_xor(e0, off); f0 += __shfl_xor(f0, off);
            d1 += __shfl_xor(d1, off); e1 += __shfl_xor(e1, off); f1 += __shfl_xor(f1, off);
        }
        if (l15 == 0) {
            const int ch = (c0 >> 1) + wgm64 + (mi << 3) + (quad << 1);
            float* dst = wsA + ((size_t)b * C_ + ch) * 3;
            atomicAdd(dst + 0, d0); atomicAdd(dst + 1, e0); atomicAdd(dst + 2, f0);
            atomicAdd(dst + 3, d1); atomicAdd(dst + 4, e1); atomicAdd(dst + 5, f1);
        }
    }
}

__global__ __launch_bounds__(512, 1) void gemm_kernel(
        const unsigned short* __restrict__ Wst,   // [1536][768] bf16, interleaved K/V
        const unsigned short* __restrict__ Xnt,   // [B][HW][C] bf16
        float* __restrict__ wsA) {
    const int x     = blockIdx.x;                 // 0..7
    const int n0    = (x >> 1) * 256;
    const int cbase = (x & 1) * 768;              // g*3*256: item c0 = cbase+item*256
    const int b     = blockIdx.y;

    const int tid  = threadIdx.x;
    const int lane = tid & 63;
    const int wave = tid >> 6;
    const int l15  = lane & 15;
    const int quad = lane >> 4;
    const int wgm64 = (wave >> 2) << 6;           // A lr offset: 0 / 64
    const int wq    = wave & 3;
    const int wnl64 = (wq & 1) << 6;              // B lr offset within half
    const int hB    = wq >> 1;                    // wave's fixed B half

    const int lb7   = l15 & 7;
    const int slot0 = (quad ^ lb7) << 3;          // k-step 0 swizzled slot (shorts)
    const int slot1 = ((quad + 4) ^ lb7) << 3;    // k-step 1

    __shared__ __align__(16) short sA[2][2][128][64];
    __shared__ __align__(16) short sB[2][2][128][64];

    // staging map: r0 = local row 0..127, chunk pre-swizzled by (r0&7)
    const int r0      = tid >> 3;
    const size_t toff = (size_t)r0 * 768 + (((tid & 7) ^ (r0 & 7)) << 3);
    const int ldsoff  = (r0 & ~7) << 6;           // wave-uniform per 8-lane row group

    const unsigned short* Bb = Xnt + (size_t)b * CHW_ + (size_t)n0 * 768;

    // tile T -> global A / B stage bases (tail clamp T-2: identical-byte rewrite)
    auto Ag = [&](int T) {
        const int Tc = (T > 35) ? (T - 2) : T;
        return Wst + (size_t)(cbase + (Tc / 12) * 256) * 768 + (size_t)(Tc % 12) * 64;
    };
    auto Bg = [&](int T) {
        const int Tc = (T > 35) ? (T - 2) : T;
        return Bb + (size_t)(Tc % 12) * 64;
    };

    f32x4 acc[8][4];
    const f32x4 zero = {0.f, 0.f, 0.f, 0.f};
    #pragma unroll
    for (int i = 0; i < 8; ++i)
        #pragma unroll
        for (int j = 0; j < 4; ++j) acc[i][j] = zero;

    bf16x8 bA[2][2], bB[4][2];

    // prologue: tile0 fully + B(1)h0/h1 + A(1)h0  (A(1)h1 comes in ph1 of t=0)
    stage_half(Ag(0),               &sA[0][0][0][0], toff, ldsoff, 128);
    stage_half(Ag(0) + 64 * 768,    &sA[0][1][0][0], toff, ldsoff, 128);
    stage_half(Bg(0),               &sB[0][0][0][0], toff, ldsoff, 64);
    stage_half(Bg(0) + 128 * 768,   &sB[0][1][0][0], toff, ldsoff, 64);
    stage_half(Bg(1),               &sB[1][0][0][0], toff, ldsoff, 64);
    stage_half(Bg(1) + 128 * 768,   &sB[1][1][0][0], toff, ldsoff, 64);
    stage_half(Ag(1),               &sA[1][0][0][0], toff, ldsoff, 128);
    asm volatile("s_waitcnt vmcnt(6)" ::: "memory");   // tile0's 8 loads done
    __builtin_amdgcn_s_barrier();
    __builtin_amdgcn_sched_barrier(0);

    #pragma unroll 1
    for (int t = 0; t < 18; ++t) {
        const int T1 = 2 * t + 1, T2 = 2 * t + 2, T3 = 2 * t + 3;
        const unsigned short* A1 = Ag(T1);
        const unsigned short* A2 = Ag(T2);
        const unsigned short* A3 = Ag(T3);
        const unsigned short* B2 = Bg(T2);
        const unsigned short* B3 = Bg(T3);

        // tile T0 (buf0), phases 1-4
        phase<0, false>(&sA[0][0][0][0], &sB[0][hB][0][0],
                        A1 + 64 * 768,  &sA[1][1][0][0], toff, ldsoff, 128,
                        l15, wgm64, wnl64, slot0, slot1, bA, bB, acc);
        phase<1, false>(&sA[0][0][0][0], nullptr,
                        B2,             &sB[0][0][0][0], toff, ldsoff, 64,
                        l15, wgm64, wnl64, slot0, slot1, bA, bB, acc);
        phase<2, false>(&sA[0][1][0][0], nullptr,
                        B2 + 128 * 768, &sB[0][1][0][0], toff, ldsoff, 64,
                        l15, wgm64, wnl64, slot0, slot1, bA, bB, acc);
        phase<3, true >(&sA[0][1][0][0], nullptr,
                        A2,             &sA[0][0][0][0], toff, ldsoff, 128,
                        l15, wgm64, wnl64, slot0, slot1, bA, bB, acc);
        // tile T1 (buf1), phases 5-8
        phase<0, false>(&sA[1][0][0][0], &sB[1][hB][0][0],
                        A2 + 64 * 768,  &sA[0][1][0][0], toff, ldsoff, 128,
                        l15, wgm64, wnl64, slot0, slot1, bA, bB, acc);
        phase<1, false>(&sA[1][0][0][0], nullptr,
                        B3,             &sB[1][0][0][0], toff, ldsoff, 64,
                        l15, wgm64, wnl64, slot0, slot1, bA, bB, acc);
        phase<2, false>(&sA[1][1][0][0], nullptr,
                        B3 + 128 * 768, &sB[1][1][0][0], toff, ldsoff, 64,
                        l15, wgm64, wnl64, slot0, slot1, bA, bB, acc);
        phase<3, true >(&sA[1][1][0][0], nullptr,
                        A3,             &sA[1][0][0][0], toff, ldsoff, 128,
                        l15, wgm64, wnl64, slot0, slot1, bA, bB, acc);

        if (t == 5 || t == 11) {    // item boundary: dump + zero acc, keep pipeline
            dump_acc(acc, wsA, b, cbase + (t / 6) * 256, wgm64, quad, l15);
        }
    }
    asm volatile("s_waitcnt vmcnt(0)" ::: "memory");   // drain dead prefetches
    dump_acc(acc, wsA, b, cbase + 512, wgm64, quad, l15);
}

// ---------------------------------------------------------------------------
// K5: out = X * gate. 8 (b,c) rows per block (32 KB/block), gate per row.
// ---------------------------------------------------------------------------
__global__ __launch_bounds__(256) void final_kernel(const float* __restrict__ X,
                                                    const float* __restrict__ wsA,
                                                    float* __restrict__ out) {
    const int bc0 = blockIdx.x * 8;
    const int tid = threadIdx.x;
    #pragma unroll
    for (int j = 0; j < 8; ++j) {
        const int bc = bc0 + j;
        const float* a = wsA + (size_t)bc * 3;
        const float pd = a[0], pk = a[1], pv = a[2];
        const float g = 0.5f * (pd / ((sqrtf(pk) + EPS_COS) * (sqrtf(pv) + EPS_COS))) + 0.5f;
        const size_t i4 = (size_t)bc * 256 + tid;
        float4 x = reinterpret_cast<const float4*>(X)[i4];
        float4 o;
        o.x = x.x * g; o.y = x.y * g; o.z = x.z * g; o.w = x.w * g;
        reinterpret_cast<float4*>(out)[i4] = o;
    }
}

// ---------------------------------------------------------------------------
extern "C" void kernel_launch(void* const* d_in, const int* in_sizes, int n_in,
                              void* d_out, int out_size, void* d_ws, size_t ws_size,
                              hipStream_t stream) {
    const float* X = (const float*)d_in[0];   // [32,768,32,32]
    const float* W = (const float*)d_in[1];   // [2304,768]
    float* out = (float*)d_out;

    // workspace layout (bytes):
    //   [0,       294912)   wsA   float[32*768*3]  (dot, nk2, nv2)
    //   [425984,  2785280)  Wst   bf16[1536*768]   (interleaved K/V rows)
    //   [2785280, 53116928) Xnt   bf16[32][1024][768]
    char* ws = (char*)d_ws;
    float* wsA           = (float*)ws;
    unsigned short* Wst  = (unsigned short*)(ws + 425984);
    unsigned short* Xnt  = (unsigned short*)(ws + 2785280);

    hipMemsetAsync(ws, 0, 294912, stream);    // zero wsA

    wconv_kernel<<<dim3(1536),   192, 0, stream>>>(W, Wst);
    norm_kernel <<<dim3(16, 32), 256, 0, stream>>>(X, Xnt);
    gemm_kernel <<<dim3(8, 32),  512, 0, stream>>>(Wst, Xnt, wsA);
    final_kernel<<<dim3(3072),   256, 0, stream>>>(X, wsA, out);
}